// Round 17
// baseline (107.323 us; speedup 1.0000x reference)
//
#include <hip/hip_runtime.h>
#include <hip/hip_bf16.h>

#define NB    16
#define NQ    2048
#define NKV   2048
#define DH    128
#define KVT   32
#define NT    64              // tiles per batch
#define TIMG  8192            // bytes per tile image (K or V^T)

typedef __attribute__((ext_vector_type(8)))  short  short8;
typedef __attribute__((ext_vector_type(4)))  float  f32x4;
typedef __attribute__((ext_vector_type(2)))  float  f32x2;
typedef __attribute__((ext_vector_type(16))) float  f32x16;
typedef __attribute__((ext_vector_type(2)))  unsigned int u32x2;

__device__ __forceinline__ unsigned short f2bf(float f) {
    union { float f; unsigned int u; } x; x.f = f;
    unsigned int r = (x.u + 0x7fffu + ((x.u >> 16) & 1u)) >> 16;
    return (unsigned short)r;
}

__device__ __forceinline__ float u2f(unsigned int u) {
    union { unsigned int u; float f; } x; x.u = u; return x.f;
}

__device__ __forceinline__ void load_lds16(const void* g, void* l) {
    __builtin_amdgcn_global_load_lds(
        (const __attribute__((address_space(1))) unsigned int*)g,
        (__attribute__((address_space(3))) unsigned int*)l, 16, 0, 0);
}

// ---- pre-convert: K -> bf16 swizzled tile images, V -> V^T bf16 images ----
// K image (per 32-kv tile): byte(kv, ch16B) = kv*256 + ((ch*16) ^ ((kv&15)<<4))
// V^T image: byte(d, w8kv)  = (d>>2)*256 + 16*((w + 4*(d&3)) ^ ((d>>2)&15))
__global__ __launch_bounds__(256)
void preconv(const float* __restrict__ kg, const float* __restrict__ vg,
             const int* __restrict__ vlg, char* __restrict__ kws,
             char* __restrict__ vws) {
    const int tid = threadIdx.x;
    const int bid = blockIdx.x;
    const int b = bid & 15, t = bid >> 4;     // t: 0..63
    const int vl = vlg[b];
    const int nt = (vl == 0) ? NT : ((vl + KVT - 1) >> 5);
    if (t >= nt) return;

    const float* kb = kg + ((size_t)b * NKV + t * KVT) * DH;
    const float* vb = vg + ((size_t)b * NKV + t * KVT) * DH;
    char* kimg = kws + (size_t)(b * NT + t) * TIMG;
    char* vimg = vws + (size_t)(b * NT + t) * TIMG;

    #pragma unroll
    for (int p = 0; p < 2; ++p) {
        int idx = p * 256 + tid;
        int kv = idx >> 4, ch = idx & 15;
        f32x4 a = *(const f32x4*)(kb + kv * DH + ch * 8);
        f32x4 c = *(const f32x4*)(kb + kv * DH + ch * 8 + 4);
        union { short8 v; unsigned short u[8]; } w;
        #pragma unroll
        for (int j = 0; j < 4; ++j) { w.u[j] = f2bf(a[j]); w.u[4 + j] = f2bf(c[j]); }
        *(short8*)(kimg + kv * 256 + ((ch * 16) ^ ((kv & 15) << 4))) = w.v;
    }
    #pragma unroll
    for (int p = 0; p < 2; ++p) {
        int task = p * 256 + tid;
        int w = task & 3, d = task >> 2;
        union { short8 v; unsigned short u[8]; } o;
        #pragma unroll
        for (int j = 0; j < 8; ++j) o.u[j] = f2bf(vb[(w * 8 + j) * DH + d]);
        int byte = (d >> 2) * 256 + 16 * ((w + 4 * (d & 3)) ^ ((d >> 2) & 15));
        *(short8*)(vimg + byte) = o.v;
    }
}

// ---- main attention: SELF-PACED waves. No barriers, no setprio. Each wave
// owns one (b, 32-q chunk, split) item and a private 32KB LDS slice
// (K 2x8KB + V 2x8KB double-buffer), paced by its own counted vmcnt.
__global__ __launch_bounds__(256, 1)
void attn32(const float* __restrict__ qg, const char* __restrict__ kws,
            const char* __restrict__ vws, const int* __restrict__ vlg,
            float* __restrict__ og, unsigned int* __restrict__ opart,
            float* __restrict__ ellg, int S, int log2S) {
    __shared__ __align__(16) char smem[131072];   // 4 waves x 32KB private

    const int tid  = threadIdx.x;
    const int lane = tid & 63;
    const int wv   = tid >> 6;
    const int l31  = lane & 31;
    const int h    = lane >> 5;

    const int item = blockIdx.x * 4 + wv;
    const int s    = item & (S - 1);
    const int rest = item >> log2S;
    const int b    = rest & 15;
    const int qc   = rest >> 4;          // 0..63: 32-q chunk
    const int q0   = qc * 32;
    const int vl   = vlg[b];
    const int nt   = (vl == 0) ? NT : ((vl + KVT - 1) >> 5);

    if (s >= nt) return;   // combine derives active splits from vl

    char* myk = smem + wv * 32768;            // K slots: 2 x 8KB
    char* myv = smem + wv * 32768 + 16384;    // V slots: 2 x 8KB

    // Q fragment (B-operand, swapped): lane holds Q[q=q0+l31][d=c*16+h*8+j]
    const float QS = 1.4426950408889634f * 0.08838834764831845f;
    short8 qw[8];
    {
        const float* qp = qg + ((size_t)b * NQ + q0 + l31) * DH + h * 8;
        #pragma unroll
        for (int c = 0; c < 8; ++c) {
            f32x4 a  = *(const f32x4*)(qp + c * 16);
            f32x4 bb = *(const f32x4*)(qp + c * 16 + 4);
            union { short8 v; unsigned short u[8]; } t;
            #pragma unroll
            for (int j = 0; j < 4; ++j) { t.u[j] = f2bf(a[j] * QS); t.u[4 + j] = f2bf(bb[j] * QS); }
            qw[c] = t.v;
        }
    }

    const float MASKV = (vl == 0) ? 0.0f : -1442695.0f;   // -1e6*log2(e)
    f32x16 oacc[4];
    #pragma unroll
    for (int d = 0; d < 4; ++d) oacc[d] = (f32x16)(0.0f);
    float esum = 0.f;

    const char* kbase = kws + (size_t)b * NT * TIMG;
    const char* vbase = vws + (size_t)b * NT * TIMG;

    // stage one tile (K 8KB + V 8KB) = 16 x 1KB loads, wave-private
    auto issue = [&](int t, int slot) {
        const char* ks = kbase + (size_t)t * TIMG;
        const char* vs = vbase + (size_t)t * TIMG;
        #pragma unroll
        for (int i = 0; i < 8; ++i)
            load_lds16(ks + i * 1024 + lane * 16, myk + slot * 8192 + i * 1024);
        #pragma unroll
        for (int i = 0; i < 8; ++i)
            load_lds16(vs + i * 1024 + lane * 16, myv + slot * 8192 + i * 1024);
    };

    issue(s, 0);
    if (s + S < nt) issue(s + S, 1);
    int p = 0;
    const int l15s = (l31 & 15) << 4;

    for (int tt = s; tt < nt; tt += S) {
        // wait for tile tt only; tile tt+S (16 loads) may stay in flight
        if (tt + S < nt) asm volatile("s_waitcnt vmcnt(16)" ::: "memory");
        else             asm volatile("s_waitcnt vmcnt(0)" ::: "memory");

        const char* kb = myk + p * 8192;
        const char* vb = myv + p * 8192;

        // ---- QK^T swapped, two independent accumulator chains ----
        f32x16 sc0 = (f32x16)(0.0f), sc1 = (f32x16)(0.0f);
        #pragma unroll
        for (int c = 0; c < 4; ++c) {
            short8 kfa = *(const short8*)(kb + l31 * 256 + (((2 * c) * 32 + h * 16) ^ l15s));
            short8 kfb = *(const short8*)(kb + l31 * 256 + (((2 * c + 1) * 32 + h * 16) ^ l15s));
            sc0 = __builtin_amdgcn_mfma_f32_32x32x16_bf16(kfa, qw[2 * c], sc0, 0, 0, 0);
            sc1 = __builtin_amdgcn_mfma_f32_32x32x16_bf16(kfb, qw[2 * c + 1], sc1, 0, 0, 0);
        }
        f32x16 sc = sc0 + sc1;

        // ---- mask (global last tile only; vl==0 masks all to 0 -> P=1) ----
        if (vl == 0 || tt == nt - 1) {
            int kvb = tt * 32 + 4 * h;
            #pragma unroll
            for (int r = 0; r < 16; ++r) {
                int kvg = kvb + (r & 3) + 8 * (r >> 2);
                if (kvg >= vl) sc[r] = MASKV;
            }
        }

        // ---- P = exp2(sc) in-register; ell partial via tree sum ----
        float pe[16];
        #pragma unroll
        for (int r = 0; r < 16; ++r) pe[r] = __builtin_amdgcn_exp2f(sc[r]);
        esum += (((pe[0] + pe[1]) + (pe[2] + pe[3])) + ((pe[4] + pe[5]) + (pe[6] + pe[7])))
              + (((pe[8] + pe[9]) + (pe[10] + pe[11])) + ((pe[12] + pe[13]) + (pe[14] + pe[15])));

        // ---- pack to bf16 + permlane32_swap -> PV B-fragments (no LDS) ----
        unsigned int A, B, C, D, E, F, G, H;
        asm("v_cvt_pk_bf16_f32 %0, %1, %2" : "=v"(A) : "v"(pe[0]),  "v"(pe[1]));
        asm("v_cvt_pk_bf16_f32 %0, %1, %2" : "=v"(B) : "v"(pe[2]),  "v"(pe[3]));
        asm("v_cvt_pk_bf16_f32 %0, %1, %2" : "=v"(C) : "v"(pe[4]),  "v"(pe[5]));
        asm("v_cvt_pk_bf16_f32 %0, %1, %2" : "=v"(D) : "v"(pe[6]),  "v"(pe[7]));
        asm("v_cvt_pk_bf16_f32 %0, %1, %2" : "=v"(E) : "v"(pe[8]),  "v"(pe[9]));
        asm("v_cvt_pk_bf16_f32 %0, %1, %2" : "=v"(F) : "v"(pe[10]), "v"(pe[11]));
        asm("v_cvt_pk_bf16_f32 %0, %1, %2" : "=v"(G) : "v"(pe[12]), "v"(pe[13]));
        asm("v_cvt_pk_bf16_f32 %0, %1, %2" : "=v"(H) : "v"(pe[14]), "v"(pe[15]));
        asm("v_permlane32_swap_b32 %0, %1" : "+v"(A), "+v"(C));
        asm("v_permlane32_swap_b32 %0, %1" : "+v"(B), "+v"(D));
        asm("v_permlane32_swap_b32 %0, %1" : "+v"(E), "+v"(G));
        asm("v_permlane32_swap_b32 %0, %1" : "+v"(F), "+v"(H));
        union { short8 v; unsigned int w[4]; } P0, P1;
        P0.w[0] = A; P0.w[1] = B; P0.w[2] = C; P0.w[3] = D;   // kv 0..15
        P1.w[0] = E; P1.w[1] = F; P1.w[2] = G; P1.w[3] = H;   // kv 16..31
        short8 pa[2] = { P0.v, P1.v };

        // ---- PV: O^T[d][q] += V^T * P ----
        #pragma unroll
        for (int dblk = 0; dblk < 4; ++dblk) {
            int quad = dblk * 8 + (l31 >> 2);
            int xk = quad & 15;
            #pragma unroll
            for (int c16 = 0; c16 < 2; ++c16) {
                int w = c16 * 2 + h;
                short8 vf = *(const short8*)(vb + quad * 256 +
                                             16 * ((w + 4 * (l31 & 3)) ^ xk));
                oacc[dblk] = __builtin_amdgcn_mfma_f32_32x32x16_bf16(vf, pa[c16], oacc[dblk], 0, 0, 0);
            }
        }

        // slot p's reads all consumed; safe to re-issue DMA into it
        asm volatile("s_waitcnt lgkmcnt(0)" ::: "memory");
        if (tt + 2 * S < nt) issue(tt + 2 * S, p);
        p ^= 1;
    }

    // ---- ell: add the other lane-half's partial (same q lives at lane^32) ----
    float ea = esum, eb;
    asm volatile("v_mov_b32 %0, %1" : "=v"(eb) : "v"(esum));
    asm("v_permlane32_swap_b32 %0, %1" : "+v"(ea), "+v"(eb));
    float ell = ea + eb;

    if (S > 1 && lane < 32)
        ellg[(size_t)s * NB * NQ + (size_t)b * NQ + q0 + lane] = ell;

    // ---- epilogue: wave-private LDS transpose O^T -> O rows (no barrier) ----
    float* tw = (float*)(smem + wv * 32768);
    if (lane < 32) tw[1088 + l31] = 1.0f / ell;
    unsigned int* opw = opart + ((size_t)s * NB * NQ + (size_t)b * NQ + q0) * 64;
    float* ogp = og + ((size_t)b * NQ + q0) * DH;

    #pragma unroll
    for (int dblk = 0; dblk < 4; ++dblk) {
        #pragma unroll
        for (int r = 0; r < 16; ++r) {
            int dd = (r & 3) + 8 * (r >> 2) + 4 * h;
            tw[l31 * 34 + dd] = oacc[dblk][r];
        }
        asm volatile("s_waitcnt lgkmcnt(0)" ::: "memory");
        #pragma unroll
        for (int pp = 0; pp < 8; ++pp) {
            int qq = pp * 4 + (lane >> 4);
            int cc = lane & 15;
            f32x2 v = *(f32x2*)(tw + qq * 34 + cc * 2);
            if (S == 1) {
                float rl = tw[1088 + qq];
                f32x2 o = { v[0] * rl, v[1] * rl };
                *(f32x2*)(ogp + (size_t)qq * DH + dblk * 32 + cc * 2) = o;
            } else {
                unsigned int w;
                asm("v_cvt_pk_bf16_f32 %0, %1, %2" : "=v"(w) : "v"(v[0]), "v"(v[1]));
                opw[(size_t)qq * 64 + dblk * 16 + cc] = w;
            }
        }
        asm volatile("s_waitcnt lgkmcnt(0)" ::: "memory");
    }
}

// ---- combine: out = (sum_s O_s) / (sum_s ell_s); active splits from vl ----
__global__ __launch_bounds__(256)
void combine(const unsigned int* __restrict__ opart, const float* __restrict__ ellg,
             const int* __restrict__ vlg, float* __restrict__ og, int S) {
    int idx = blockIdx.x * 256 + threadIdx.x;    // NB*NQ*32 threads
    int row = idx >> 5;                           // b*NQ + q
    int c   = idx & 31;                           // d = c*4 .. c*4+3
    int b   = row >> 11;
    int vl  = vlg[b];
    int nact = (vl == 0) ? NT : ((vl + KVT - 1) >> 5);
    if (nact > S) nact = S;
    float a0 = 0.f, a1 = 0.f, a2 = 0.f, a3 = 0.f, l = 0.f;
    for (int s = 0; s < nact; ++s) {
        l += ellg[(size_t)s * NB * NQ + row];
        u32x2 w = *(const u32x2*)(opart + ((size_t)s * NB * NQ + row) * 64 + c * 2);
        a0 += u2f(w[0] << 16); a1 += u2f(w[0] & 0xffff0000u);
        a2 += u2f(w[1] << 16); a3 += u2f(w[1] & 0xffff0000u);
    }
    float rl = 1.0f / l;
    f32x4 o = { a0 * rl, a1 * rl, a2 * rl, a3 * rl };
    *(f32x4*)(og + (size_t)row * DH + c * 4) = o;
}

extern "C" void kernel_launch(void* const* d_in, const int* in_sizes, int n_in,
                              void* d_out, int out_size, void* d_ws, size_t ws_size,
                              hipStream_t stream) {
    const float* q  = (const float*)d_in[0];
    const float* k  = (const float*)d_in[1];
    const float* v  = (const float*)d_in[2];
    const int*   vl = (const int*)d_in[3];
    float* o = (float*)d_out;

    const size_t IMG     = (size_t)NB * NT * TIMG;          // 8 MB per image set
    const size_t ELL_OFF = 2 * IMG;                         // 16 MB
    const size_t ELL_MAX = (size_t)4 * NB * NQ * 4;         // 512 KB
    const size_t OP_OFF  = ELL_OFF + ELL_MAX;
    const size_t OP_ONE  = (size_t)NB * NQ * DH * 2;        // 8 MB per split (bf16)

    int S = 1, log2S = 0;
    if      (ws_size >= OP_OFF + 4 * OP_ONE) { S = 4; log2S = 2; }
    else if (ws_size >= OP_OFF + 2 * OP_ONE) { S = 2; log2S = 1; }

    char* kws = (char*)d_ws;
    char* vws = (char*)d_ws + IMG;
    float* ellg = (float*)((char*)d_ws + ELL_OFF);
    unsigned int* opart = (unsigned int*)((char*)d_ws + OP_OFF);

    preconv<<<dim3(NB * NT), dim3(256), 0, stream>>>(k, v, vl, kws, vws);
    attn32<<<dim3(256 * S), dim3(256), 0, stream>>>(q, kws, vws, vl, o, opart, ellg, S, log2S);
    if (S > 1)
        combine<<<dim3(NB * NQ * 32 / 256), dim3(256), 0, stream>>>(opart, ellg, vl, o, S);
}

// Round 18
// 60.429 us; speedup vs baseline: 1.7760x; 1.7760x over previous
//
#include <hip/hip_runtime.h>
#include <hip/hip_bf16.h>

#define NB    16
#define NQ    2048
#define NKV   2048
#define DH    128
#define KVT   32
#define NT    64              // tiles per batch
#define TIMG  8192            // bytes per tile image (K or V^T)

typedef __attribute__((ext_vector_type(8)))  short  short8;
typedef __attribute__((ext_vector_type(4)))  float  f32x4;
typedef __attribute__((ext_vector_type(2)))  float  f32x2;
typedef __attribute__((ext_vector_type(16))) float  f32x16;
typedef __attribute__((ext_vector_type(2)))  unsigned int u32x2;

__device__ __forceinline__ unsigned short f2bf(float f) {
    union { float f; unsigned int u; } x; x.f = f;
    unsigned int r = (x.u + 0x7fffu + ((x.u >> 16) & 1u)) >> 16;
    return (unsigned short)r;
}

__device__ __forceinline__ float u2f(unsigned int u) {
    union { unsigned int u; float f; } x; x.u = u; return x.f;
}

__device__ __forceinline__ void load_lds16(const void* g, void* l) {
    __builtin_amdgcn_global_load_lds(
        (const __attribute__((address_space(1))) unsigned int*)g,
        (__attribute__((address_space(3))) unsigned int*)l, 16, 0, 0);
}

// ---- pre-convert: K -> bf16 swizzled tile images, V -> V^T bf16 images ----
// XCD-affine: consecutive bids round-robin XCDs, so bid&7 selects the XCD.
// Batches {2j, 2j+1} are produced AND consumed on XCD j -> their 2MB of
// images stay resident in that XCD's 4MB L2.
__global__ __launch_bounds__(256)
void preconv(const float* __restrict__ kg, const float* __restrict__ vg,
             const int* __restrict__ vlg, char* __restrict__ kws,
             char* __restrict__ vws) {
    const int tid = threadIdx.x;
    const int bid = blockIdx.x;
    const int j = bid & 7;                    // XCD
    const int k = bid >> 3;                   // 0..127
    const int b = j * 2 + (k & 1);
    const int t = k >> 1;                     // 0..63
    const int vl = vlg[b];
    const int nt = (vl == 0) ? NT : ((vl + KVT - 1) >> 5);
    if (t >= nt) return;

    const float* kb = kg + ((size_t)b * NKV + t * KVT) * DH;
    const float* vb = vg + ((size_t)b * NKV + t * KVT) * DH;
    char* kimg = kws + (size_t)(b * NT + t) * TIMG;
    char* vimg = vws + (size_t)(b * NT + t) * TIMG;

    #pragma unroll
    for (int p = 0; p < 2; ++p) {
        int idx = p * 256 + tid;
        int kv = idx >> 4, ch = idx & 15;
        f32x4 a = *(const f32x4*)(kb + kv * DH + ch * 8);
        f32x4 c = *(const f32x4*)(kb + kv * DH + ch * 8 + 4);
        union { short8 v; unsigned short u[8]; } w;
        #pragma unroll
        for (int jj = 0; jj < 4; ++jj) { w.u[jj] = f2bf(a[jj]); w.u[4 + jj] = f2bf(c[jj]); }
        *(short8*)(kimg + kv * 256 + ((ch * 16) ^ ((kv & 15) << 4))) = w.v;
    }
    #pragma unroll
    for (int p = 0; p < 2; ++p) {
        int task = p * 256 + tid;
        int w = task & 3, d = task >> 2;
        union { short8 v; unsigned short u[8]; } o;
        #pragma unroll
        for (int jj = 0; jj < 8; ++jj) o.u[jj] = f2bf(vb[(w * 8 + jj) * DH + d]);
        int byte = (d >> 2) * 256 + 16 * ((w + 4 * (d & 3)) ^ ((d >> 2) & 15));
        *(short8*)(vimg + byte) = o.v;
    }
}

// ---- main attention: r16 body (depth-2 counted vmcnt, 3-buf) + XCD-affine
// decode: XCD j only ever stages batches {2j, 2j+1} -> K/V L2-resident.
__global__ __launch_bounds__(256, 3)
void attn32(const float* __restrict__ qg, const char* __restrict__ kws,
            const char* __restrict__ vws, const int* __restrict__ vlg,
            float* __restrict__ og, unsigned int* __restrict__ opart,
            float* __restrict__ ellg, int S) {
    __shared__ __align__(16) char smem[49152];   // K 3x8KB @0, V 3x8KB @24576

    const int tid  = threadIdx.x;
    const int lane = tid & 63;
    const int wv   = tid >> 6;
    const int l31  = lane & 31;
    const int h    = lane >> 5;

    const int bid = blockIdx.x;
    const int j  = bid & 7;               // XCD
    const int k  = bid >> 3;              // 0 .. 16*S-1 per batch-pair
    const int b  = j * 2 + (k & 1);
    const int qt = (k >> 1) & 15;         // 16 q-tiles of 128 rows
    const int s  = k >> 5;                // split id (0..S-1)
    const int q0 = qt * 128 + wv * 32;
    const int vl = vlg[b];
    const int nt = (vl == 0) ? NT : ((vl + KVT - 1) >> 5);

    if (s >= nt) return;   // combine derives active splits from vl

    // Q fragment (B-operand, swapped): lane holds Q[q=q0+l31][d=c*16+h*8+j]
    const float QS = 1.4426950408889634f * 0.08838834764831845f;
    short8 qw[8];
    {
        const float* qp = qg + ((size_t)b * NQ + q0 + l31) * DH + h * 8;
        #pragma unroll
        for (int c = 0; c < 8; ++c) {
            f32x4 a  = *(const f32x4*)(qp + c * 16);
            f32x4 bb = *(const f32x4*)(qp + c * 16 + 4);
            union { short8 v; unsigned short u[8]; } t;
            #pragma unroll
            for (int jj = 0; jj < 4; ++jj) { t.u[jj] = f2bf(a[jj] * QS); t.u[4 + jj] = f2bf(bb[jj] * QS); }
            qw[c] = t.v;
        }
    }

    const float MASKV = (vl == 0) ? 0.0f : -1442695.0f;   // -1e6*log2(e)
    f32x16 oacc[4];
    #pragma unroll
    for (int d = 0; d < 4; ++d) oacc[d] = (f32x16)(0.0f);
    float esum = 0.f;

    const char* kbase = kws + (size_t)b * NT * TIMG;
    const char* vbase = vws + (size_t)b * NT * TIMG;

    // stage one tile (K 8KB + V 8KB) into 3-deep slots; 4 loads/wave
    auto issue = [&](int t, int slot) {
        const char* ks = kbase + (size_t)t * TIMG;
        const char* vs = vbase + (size_t)t * TIMG;
        char* kd = smem + slot * 8192;
        char* vd = smem + 24576 + slot * 8192;
        #pragma unroll
        for (int i = 0; i < 2; ++i) {
            int off = wv * 2048 + i * 1024;
            load_lds16(ks + off + lane * 16, kd + off);
        }
        #pragma unroll
        for (int i = 0; i < 2; ++i) {
            int off = wv * 2048 + i * 1024;
            load_lds16(vs + off + lane * 16, vd + off);
        }
    };

    // depth-2 prologue: tiles s and s+S in flight before the first window
    issue(s, 0);
    if (s + S < nt) issue(s + S, 1);
    int slot = 0;
    const int l15s = (l31 & 15) << 4;

    for (int tt = s; tt < nt; tt += S) {
        // counted wait: tile tt's 4 loads retired; tile tt+S's 4 may stay in flight
        if (tt + S < nt) asm volatile("s_waitcnt vmcnt(4)" ::: "memory");
        else             asm volatile("s_waitcnt vmcnt(0)" ::: "memory");
        __syncthreads();   // tile tt staged by all waves; slot (slot+2)%3 readers done

        int t2 = tt + 2 * S;
        if (t2 < nt) issue(t2, slot == 0 ? 2 : slot - 1);   // (slot+2)%3

        const char* kb = smem + slot * 8192;
        const char* vb = smem + 24576 + slot * 8192;

        // ---- QK^T swapped: sc[r] = S^T[kv=tt*32+(r&3)+8*(r>>2)+4h][q=q0+l31] ----
        f32x16 sc = (f32x16)(0.0f);
        __builtin_amdgcn_s_setprio(1);
        #pragma unroll
        for (int c = 0; c < 8; ++c) {
            short8 kf = *(const short8*)(kb + l31 * 256 + ((c * 32 + h * 16) ^ l15s));
            sc = __builtin_amdgcn_mfma_f32_32x32x16_bf16(kf, qw[c], sc, 0, 0, 0);
        }
        __builtin_amdgcn_s_setprio(0);

        // ---- mask (global last tile only; vl==0 masks all to 0 -> P=1) ----
        if (vl == 0 || tt == nt - 1) {
            int kvb = tt * 32 + 4 * h;
            #pragma unroll
            for (int r = 0; r < 16; ++r) {
                int kvg = kvb + (r & 3) + 8 * (r >> 2);
                if (kvg >= vl) sc[r] = MASKV;
            }
        }

        // ---- P = exp2(sc) in-register; ell partial via tree sum ----
        float pe[16];
        #pragma unroll
        for (int r = 0; r < 16; ++r) pe[r] = __builtin_amdgcn_exp2f(sc[r]);
        esum += (((pe[0] + pe[1]) + (pe[2] + pe[3])) + ((pe[4] + pe[5]) + (pe[6] + pe[7])))
              + (((pe[8] + pe[9]) + (pe[10] + pe[11])) + ((pe[12] + pe[13]) + (pe[14] + pe[15])));

        // ---- pack to bf16 + permlane32_swap -> PV B-fragments (no LDS!) ----
        unsigned int A, B, C, D, E, F, G, H;
        asm("v_cvt_pk_bf16_f32 %0, %1, %2" : "=v"(A) : "v"(pe[0]),  "v"(pe[1]));
        asm("v_cvt_pk_bf16_f32 %0, %1, %2" : "=v"(B) : "v"(pe[2]),  "v"(pe[3]));
        asm("v_cvt_pk_bf16_f32 %0, %1, %2" : "=v"(C) : "v"(pe[4]),  "v"(pe[5]));
        asm("v_cvt_pk_bf16_f32 %0, %1, %2" : "=v"(D) : "v"(pe[6]),  "v"(pe[7]));
        asm("v_cvt_pk_bf16_f32 %0, %1, %2" : "=v"(E) : "v"(pe[8]),  "v"(pe[9]));
        asm("v_cvt_pk_bf16_f32 %0, %1, %2" : "=v"(F) : "v"(pe[10]), "v"(pe[11]));
        asm("v_cvt_pk_bf16_f32 %0, %1, %2" : "=v"(G) : "v"(pe[12]), "v"(pe[13]));
        asm("v_cvt_pk_bf16_f32 %0, %1, %2" : "=v"(H) : "v"(pe[14]), "v"(pe[15]));
        asm("v_permlane32_swap_b32 %0, %1" : "+v"(A), "+v"(C));
        asm("v_permlane32_swap_b32 %0, %1" : "+v"(B), "+v"(D));
        asm("v_permlane32_swap_b32 %0, %1" : "+v"(E), "+v"(G));
        asm("v_permlane32_swap_b32 %0, %1" : "+v"(F), "+v"(H));
        union { short8 v; unsigned int w[4]; } P0, P1;
        P0.w[0] = A; P0.w[1] = B; P0.w[2] = C; P0.w[3] = D;   // kv chunk 0..15
        P1.w[0] = E; P1.w[1] = F; P1.w[2] = G; P1.w[3] = H;   // kv chunk 16..31
        short8 pa[2] = { P0.v, P1.v };

        // ---- PV: O^T[d][q] += V^T * P ----
        __builtin_amdgcn_s_setprio(1);
        #pragma unroll
        for (int dblk = 0; dblk < 4; ++dblk) {
            int quad = dblk * 8 + (l31 >> 2);
            int xk = quad & 15;
            #pragma unroll
            for (int c16 = 0; c16 < 2; ++c16) {
                int w = c16 * 2 + h;
                short8 vf = *(const short8*)(vb + quad * 256 +
                                             16 * ((w + 4 * (l31 & 3)) ^ xk));
                oacc[dblk] = __builtin_amdgcn_mfma_f32_32x32x16_bf16(vf, pa[c16], oacc[dblk], 0, 0, 0);
            }
        }
        __builtin_amdgcn_s_setprio(0);

        slot = (slot == 2) ? 0 : slot + 1;
    }

    // ---- ell: add the other lane-half's partial (same q lives at lane^32) ----
    float ea = esum, eb;
    asm volatile("v_mov_b32 %0, %1" : "=v"(eb) : "v"(esum));
    asm("v_permlane32_swap_b32 %0, %1" : "+v"(ea), "+v"(eb));
    float ell = ea + eb;

    __syncthreads();   // staging/compute done; smem reusable for transpose

    if (S > 1 && lane < 32)
        ellg[(size_t)s * NB * NQ + (size_t)b * NQ + q0 + lane] = ell;

    // ---- epilogue: per-wave LDS transpose O^T -> O rows, coalesced stores ----
    float* tw = (float*)smem + wv * 1120;          // 34-stride region + ell row
    if (lane < 32) tw[1088 + l31] = 1.0f / ell;
    unsigned int* opw = opart + ((size_t)s * NB * NQ + (size_t)b * NQ + q0) * 64;
    float* ogp = og + ((size_t)b * NQ + q0) * DH;

    #pragma unroll
    for (int dblk = 0; dblk < 4; ++dblk) {
        #pragma unroll
        for (int r = 0; r < 16; ++r) {
            int dd = (r & 3) + 8 * (r >> 2) + 4 * h;
            tw[l31 * 34 + dd] = oacc[dblk][r];
        }
        asm volatile("s_waitcnt lgkmcnt(0)" ::: "memory");
        #pragma unroll
        for (int pp = 0; pp < 8; ++pp) {
            int qq = pp * 4 + (lane >> 4);
            int cc = lane & 15;
            f32x2 v = *(f32x2*)(tw + qq * 34 + cc * 2);
            if (S == 1) {
                float rl = tw[1088 + qq];
                f32x2 o = { v[0] * rl, v[1] * rl };
                *(f32x2*)(ogp + (size_t)qq * DH + dblk * 32 + cc * 2) = o;
            } else {
                unsigned int w;
                asm("v_cvt_pk_bf16_f32 %0, %1, %2" : "=v"(w) : "v"(v[0]), "v"(v[1]));
                opw[(size_t)qq * 64 + dblk * 16 + cc] = w;
            }
        }
        asm volatile("s_waitcnt lgkmcnt(0)" ::: "memory");
    }
}

// ---- combine: out = (sum_s O_s) / (sum_s ell_s); active splits from vl ----
__global__ __launch_bounds__(256)
void combine(const unsigned int* __restrict__ opart, const float* __restrict__ ellg,
             const int* __restrict__ vlg, float* __restrict__ og, int S) {
    int idx = blockIdx.x * 256 + threadIdx.x;    // NB*NQ*32 threads
    int row = idx >> 5;                           // b*NQ + q
    int c   = idx & 31;                           // d = c*4 .. c*4+3
    int b   = row >> 11;
    int vl  = vlg[b];
    int nact = (vl == 0) ? NT : ((vl + KVT - 1) >> 5);
    if (nact > S) nact = S;
    float a0 = 0.f, a1 = 0.f, a2 = 0.f, a3 = 0.f, l = 0.f;
    for (int s = 0; s < nact; ++s) {
        l += ellg[(size_t)s * NB * NQ + row];
        u32x2 w = *(const u32x2*)(opart + ((size_t)s * NB * NQ + row) * 64 + c * 2);
        a0 += u2f(w[0] << 16); a1 += u2f(w[0] & 0xffff0000u);
        a2 += u2f(w[1] << 16); a3 += u2f(w[1] & 0xffff0000u);
    }
    float rl = 1.0f / l;
    f32x4 o = { a0 * rl, a1 * rl, a2 * rl, a3 * rl };
    *(f32x4*)(og + (size_t)row * DH + c * 4) = o;
}

extern "C" void kernel_launch(void* const* d_in, const int* in_sizes, int n_in,
                              void* d_out, int out_size, void* d_ws, size_t ws_size,
                              hipStream_t stream) {
    const float* q  = (const float*)d_in[0];
    const float* k  = (const float*)d_in[1];
    const float* v  = (const float*)d_in[2];
    const int*   vl = (const int*)d_in[3];
    float* o = (float*)d_out;

    const size_t IMG     = (size_t)NB * NT * TIMG;          // 8 MB per image set
    const size_t ELL_OFF = 2 * IMG;                         // 16 MB
    const size_t ELL_MAX = (size_t)4 * NB * NQ * 4;         // 512 KB
    const size_t OP_OFF  = ELL_OFF + ELL_MAX;
    const size_t OP_ONE  = (size_t)NB * NQ * DH * 2;        // 8 MB per split (bf16)

    int S = 1;
    if      (ws_size >= OP_OFF + 4 * OP_ONE) S = 4;
    else if (ws_size >= OP_OFF + 2 * OP_ONE) S = 2;

    char* kws = (char*)d_ws;
    char* vws = (char*)d_ws + IMG;
    float* ellg = (float*)((char*)d_ws + ELL_OFF);
    unsigned int* opart = (unsigned int*)((char*)d_ws + OP_OFF);

    preconv<<<dim3(NB * NT), dim3(256), 0, stream>>>(k, v, vl, kws, vws);
    attn32<<<dim3(8 * 32 * S), dim3(256), 0, stream>>>(q, kws, vws, vl, o, opart, ellg, S);
    if (S > 1)
        combine<<<dim3(NB * NQ * 32 / 256), dim3(256), 0, stream>>>(opart, ellg, vl, o, S);
}